// Round 8
// baseline (445.600 us; speedup 1.0000x reference)
//
#include <hip/hip_runtime.h>

// GATConv on MI355X. Inputs fp32, indices int32, OUTPUT fp32.
// bf16 for MFMA GEMM inputs + xls workspace; fp32 accumulation everywhere.
// R15: hybrid gemm -- x in REGISTERS (R7's good half: per-lane contiguous
// 32B runs, loaded once, no staging/conflicts), W in LDS (R6's good half:
// shared operand, one cooperative 34.8KB stage from L2-hot Wtg; R7 proved
// W-from-global starves MFMA: 64 VGPR -> no loads in flight). y-passes
// SPLIT into separate blocks: stage-W, sync, MFMA, store -- minimal
// critical path, 4 blocks/CU (was 3 @ 52KB). EPB back to 8192 (R6's 2048
// halved bin scatter locality). binned buffer ELIMINATED: bin writes packed
// entries into colsort windows; csr sorts in-place via LDS (-11MB ws).

typedef short bfvec8 __attribute__((ext_vector_type(8)));  // 8 bf16 (4 VGPRs)
typedef float f32x4  __attribute__((ext_vector_type(4)));

#define BK 128      // nodes per bucket (bucket id = row >> 7)
#define CAPC 3584   // static bucket capacity (mean 2048, sd 45 -> +34 sigma)
#define EPB 8192    // edges per bin sub-block
#define REC 256     // xls record bytes: 128 bf16 x_l, 256B-aligned
#define BSTR 16     // bcur stride in ints: one counter per 64B line

__device__ __forceinline__ unsigned short f2bf(float f) {
  union { float f; unsigned int i; } v; v.f = f;
  unsigned int r = v.i + 0x7fffu + ((v.i >> 16) & 1u);  // RNE
  return (unsigned short)(r >> 16);
}

// ---------------------------------------------------------------------------
// Wt[y][n][k] bf16, n<128 -> W^T. y=0 rows 128..131 = a1w^T*log2e,
// 132..135 = a2w^T*log2e. Blocks (x<8, y=0) also init bcur (folded init_k).
__global__ __launch_bounds__(128) void wprep_k(
    const float* __restrict__ Wl, const float* __restrict__ Wr,
    const float* __restrict__ a1w, const float* __restrict__ a2w,
    unsigned short* __restrict__ Wtg, int* __restrict__ bcur, int NBK)
{
  const int n = blockIdx.x;      // 0..135
  const int y = blockIdx.y;      // 0..1
  const int k = threadIdx.x;     // 0..127
  if (y == 0 && n < 8) {
    int b = n * 128 + k;
    if (b < NBK) bcur[b * BSTR] = b * CAPC;
  }
  const float* W = y ? Wr : Wl;
  const float LOG2E = 1.4426950408889634f;
  float v;
  if (n < 128)      v = W[(size_t)k * 128 + n];
  else if (y)       v = 0.f;                                  // unused
  else if (n < 132) v = a1w[k * 4 + (n - 128)] * LOG2E;
  else              v = a2w[k * 4 + (n - 132)] * LOG2E;
  Wtg[((size_t)y * 136 + n) * 128 + k] = f2bf(v);
}

// ---------------------------------------------------------------------------
// FUSED kernel: role-split blocks (bin every S-th block, S passed in).
//   role GEMM: 64 x-rows, ONE y-pass per block (y = sub&1).
//     W staged once into LDS [128][136] (2-way bank aliasing = free);
//     x-fragments in regs (afx[4], loaded once); a-tile rows (y=0) in regs.
//     One __syncthreads total. SWAPPED MFMA (D^T) -> vectorized stores.
//     y=0: xls = x@W_l (bf16), s1 = x@a1w', s2 = x@a2w'; y=1: out=x@W_r+bias.
//   role BIN: ticketed binning of EPB edges -> packed entries written
//     DIRECTLY into colsort bucket windows: (r&127)<<17 | c.
__global__ __launch_bounds__(256) void gemm_bin_k(
    const float* __restrict__ x, const unsigned short* __restrict__ Wtg,
    const float* __restrict__ bias,
    char* __restrict__ xls, float* __restrict__ out,
    float* __restrict__ s1, float* __restrict__ s2, int N,
    const int* __restrict__ row, const int* __restrict__ col,
    int* __restrict__ bcur, unsigned int* __restrict__ colsort,
    int E, int NBK, int binBlocks, int gemmBlocks, int S)
{
  __shared__ __align__(16) char raw[34816];   // gemm: Ws[128][136]; bin: h/base
  const int bid = blockIdx.x;
  const int t = threadIdx.x;
  const bool isbin = (bid % S == 0) && (bid / S < binBlocks);

  if (isbin) {
    // ---------------- BIN role ----------------
    int* h    = (int*)raw;            // [NBK] counts / cursors
    int* base = (int*)(raw + 4096);   // [NBK] global bases
    const int sub = bid / S;
    const int e0 = sub * EPB;
    const int e1 = min(e0 + EPB, E);

    int rloc[32];
    for (int i = t; i < NBK; i += 256) h[i] = 0;
    __syncthreads();
    #pragma unroll
    for (int k = 0; k < 32; ++k) {
      int e = e0 + t + (k << 8);
      rloc[k] = (e < e1) ? row[e] : -1;
      if (rloc[k] >= 0) atomicAdd(&h[rloc[k] >> 7], 1);
    }
    __syncthreads();
    for (int i = t; i < NBK; i += 256) {
      int c = h[i];
      base[i] = c ? atomicAdd(&bcur[i * BSTR], c) : 0;
    }
    __syncthreads();
    for (int i = t; i < NBK; i += 256) h[i] = 0;   // reuse as local cursor
    __syncthreads();
    #pragma unroll
    for (int k = 0; k < 32; ++k) {
      int e = e0 + t + (k << 8);
      if (e < e1) {
        int r = rloc[k];
        unsigned c = (unsigned)col[e];
        int b = r >> 7;
        int rk = atomicAdd(&h[b], 1);
        colsort[base[b] + rk] = ((unsigned)(r & 127) << 17) | c;
      }
    }
    return;
  }

  // ---------------- GEMM role (one y-pass) ----------------
  unsigned short (*Ws)[136] = (unsigned short(*)[136])raw;
  const int sub = bid - min(bid / S + 1, binBlocks);
  if (sub >= gemmBlocks) return;
  const int y  = sub & 1;
  const int n0 = (sub >> 1) * 64;
  const unsigned short* Wt = Wtg + (size_t)y * 136 * 128;

  // cooperative W stage: 128 rows x 128 cols bf16 -> LDS (+8 pad)
  for (int i = t; i < 2048; i += 256) {
    int nr = i >> 4, kc = (i & 15) << 3;
    *(uint4*)&Ws[nr][kc] = *(const uint4*)&Wt[(size_t)nr * 128 + kc];
  }

  const int w    = t >> 6;
  const int lane = t & 63;
  const int m    = lane & 15;
  const int quad = lane >> 4;
  const int nrow = n0 + 16 * w + m;   // this lane's single output row
  const int kb   = quad * 8;          // k-offset within each 32-wide chunk

  // x fragments: 8 fp32 -> bf16x8 per k-chunk, loaded ONCE (overlaps stage)
  bfvec8 afx[4];
  #pragma unroll
  for (int kc4 = 0; kc4 < 4; ++kc4) {
    f32x4 u = (f32x4){0.f, 0.f, 0.f, 0.f};
    f32x4 v = (f32x4){0.f, 0.f, 0.f, 0.f};
    if (nrow < N) {
      const float* xp = &x[(size_t)nrow * 128 + kc4 * 32 + kb];
      u = *(const f32x4*)xp;
      v = *(const f32x4*)(xp + 4);
    }
    bfvec8 a;
    a[0] = (short)f2bf(u[0]); a[1] = (short)f2bf(u[1]);
    a[2] = (short)f2bf(u[2]); a[3] = (short)f2bf(u[3]);
    a[4] = (short)f2bf(v[0]); a[5] = (short)f2bf(v[1]);
    a[6] = (short)f2bf(v[2]); a[7] = (short)f2bf(v[3]);
    afx[kc4] = a;
  }

  // a-tile rows (y=0) straight from L2-hot global into regs
  bfvec8 ar[4];
  if (y == 0) {
    int arow = 128 + (m < 8 ? m : 7);
    #pragma unroll
    for (int kc4 = 0; kc4 < 4; ++kc4)
      ar[kc4] = *(const bfvec8*)&Wt[(size_t)arow * 128 + kc4 * 32 + kb];
  }

  __syncthreads();

  f32x4 acc[9];
  #pragma unroll
  for (int i = 0; i < 9; ++i) acc[i] = (f32x4){0.f, 0.f, 0.f, 0.f};

  #pragma unroll
  for (int kc4 = 0; kc4 < 4; ++kc4) {
    const int kc = kc4 * 32 + kb;
    #pragma unroll
    for (int nt = 0; nt < 8; ++nt) {
      bfvec8 bfr = *(const bfvec8*)&Ws[nt * 16 + m][kc];
      acc[nt] = __builtin_amdgcn_mfma_f32_16x16x32_bf16(bfr, afx[kc4], acc[nt], 0, 0, 0);
    }
    if (y == 0)
      acc[8] = __builtin_amdgcn_mfma_f32_16x16x32_bf16(ar[kc4], afx[kc4], acc[8], 0, 0, 0);
  }

  if (nrow < N) {
    if (y) {
      #pragma unroll
      for (int nt = 0; nt < 8; ++nt) {
        int c = nt * 16 + quad * 4;
        float4 b4 = *(const float4*)&bias[c];
        float4 v = make_float4(acc[nt][0] + b4.x, acc[nt][1] + b4.y,
                               acc[nt][2] + b4.z, acc[nt][3] + b4.w);
        *(float4*)&out[(size_t)nrow * 128 + c] = v;
      }
    } else {
      #pragma unroll
      for (int nt = 0; nt < 8; ++nt) {
        int c = nt * 16 + quad * 4;
        unsigned lo = (unsigned)f2bf(acc[nt][0]) | ((unsigned)f2bf(acc[nt][1]) << 16);
        unsigned hi = (unsigned)f2bf(acc[nt][2]) | ((unsigned)f2bf(acc[nt][3]) << 16);
        *(uint2*)(xls + ((size_t)nrow << 8) + 2 * c) = make_uint2(lo, hi);
      }
      if (quad == 0) *(f32x4*)&s1[nrow * 4] = acc[8];      // a-cols 0..3
      else if (quad == 1) *(f32x4*)&s2[nrow * 4] = acc[8]; // a-cols 4..7
    }
  }
}

// ---------------------------------------------------------------------------
// Block b owns bucket b (128 nodes): reads its colsort window into LDS
// (packed (rlo<<17)|c entries), hist+scan -> offs/deg, then scatters the
// SORTED premultiplied cols (c<<8) back IN PLACE over the same window.
__global__ __launch_bounds__(256) void csr_k(
    const int* __restrict__ bcur, int* __restrict__ offs, int* __restrict__ deg,
    unsigned int* __restrict__ colsort, int N)
{
  __shared__ unsigned ecache[CAPC];   // 14.3KB
  __shared__ int h[BK];
  __shared__ int sh[BK];
  const int t = threadIdx.x;
  const int b = blockIdx.x;
  const int lo = b * BK;
  const int e0 = b * CAPC;
  const int e1 = bcur[b * BSTR];   // e0 + cnt

  if (t < BK) h[t] = 0;
  __syncthreads();
  for (int i = e0 + t; i < e1; i += 256) {   // full window read BEFORE writes
    unsigned p = colsort[i];
    ecache[i - e0] = p;
    atomicAdd(&h[p >> 17], 1);
  }
  __syncthreads();

  int v = 0;
  if (t < BK) { v = h[t]; sh[t] = v; }
  __syncthreads();
  for (int off = 1; off < BK; off <<= 1) {
    int tv = (t < BK && t >= off) ? sh[t - off] : 0;
    __syncthreads();
    if (t < BK) sh[t] += tv;
    __syncthreads();
  }
  if (t < BK) {
    int ex = sh[t] - v;
    int node = lo + t;
    if (node < N) { offs[node] = e0 + ex; deg[node] = v; }
    h[t] = ex;          // reuse as cursor
  }
  __syncthreads();
  const int cnt = e1 - e0;
  for (int i = t; i < cnt; i += 256) {
    unsigned p = ecache[i];
    int rlo = p >> 17;
    unsigned c = p & 0x1FFFFu;
    int pos = atomicAdd(&h[rlo], 1);
    colsort[e0 + pos] = c << 8;    // premultiplied byte base (REC=256)
  }
}

// ---------------------------------------------------------------------------
// One wave per node. Lane l: dims {2l,2l+1}, head l>>4.
// 8-chunks, softmax de-duplicated: lanes compute wv = exp2(leaky(s1+s2)) for
// (edge (l>>2)&7, head l&3) -- ONE v_exp_f32 per chunk -- then 8 shfl
// broadcast wv[j] to accumulation lanes. Tail: ONE masked chunk.
__global__ __launch_bounds__(256) void agg_k(const int* __restrict__ offs,
    const int* __restrict__ deg, const unsigned int* __restrict__ colsort,
    const float* __restrict__ s1, const float* __restrict__ s2,
    const char* __restrict__ xls, float* __restrict__ out, int N)
{
  const int lane = threadIdx.x & 63;
  const int n = blockIdx.x * 4 + (threadIdx.x >> 6);
  if (n >= N) return;
  const int e0 = offs[n], e1 = e0 + deg[n];
  const int h  = lane >> 4;          // accumulation head
  const int hp = lane & 3;           // softmax head
  const int jj = (lane >> 2) & 7;    // softmax edge slot
  const float s1c = s1[n * 4 + hp];                // pre-scaled by log2e
  const unsigned lane4 = (unsigned)(lane << 2);
  const unsigned hp4   = (unsigned)(hp << 2);
  const char* s2b = (const char*)s2;

  float acc0 = 0.f, acc1 = 0.f, wsum = 0.f;
  int i0 = e0;
  for (; i0 + 8 <= e1; i0 += 8) {
    // softmax phase: 32 (edge,head) pairs across lanes (upper half mirrors)
    unsigned csl = colsort[i0 + jj];                       // 8 distinct addrs
    float z2 = *(const float*)(s2b + ((csl >> 4) + hp4));  // L2-resident table
    float z = s1c + z2;
    z = fmaxf(z, 0.2f * z);                                // leaky (pos scale ok)
    float wv = exp2f(z);                                   // ONE v_exp_f32

    // gather phase: 256B-aligned records, 8 independent loads in flight
    unsigned cs[8];
    #pragma unroll
    for (int j = 0; j < 8; ++j) cs[j] = colsort[i0 + j];   // broadcast
    unsigned pv[8];
    #pragma unroll
    for (int j = 0; j < 8; ++j)
      pv[j] = *(const unsigned*)(xls + (cs[j] + lane4));

    // broadcast + accumulate
    #pragma unroll
    for (int j = 0; j < 8; ++j) {
      float wj = __shfl(wv, (j << 2) | h);                 // ds_bpermute
      wsum += wj;
      union { unsigned u; float f; } lo, hi;
      lo.u = pv[j] << 16;
      hi.u = pv[j] & 0xffff0000u;
      acc0 += wj * lo.f;
      acc1 += wj * hi.f;
    }
  }
  if (i0 < e1) {                     // masked parallel tail chunk (rem 1..7)
    const int rem = e1 - i0;
    unsigned csl = colsort[i0 + (jj < rem ? jj : rem - 1)];
    float z2 = *(const float*)(s2b + ((csl >> 4) + hp4));
    float z = s1c + z2;
    z = fmaxf(z, 0.2f * z);
    float wv = (jj < rem) ? exp2f(z) : 0.f;

    unsigned cs[8];
    #pragma unroll
    for (int j = 0; j < 8; ++j) cs[j] = colsort[i0 + (j < rem ? j : rem - 1)];
    unsigned pv[8];
    #pragma unroll
    for (int j = 0; j < 8; ++j)
      pv[j] = *(const unsigned*)(xls + (cs[j] + lane4));

    #pragma unroll
    for (int j = 0; j < 8; ++j) {
      float wj = __shfl(wv, (j << 2) | h);                 // 0 for j>=rem
      wsum += wj;
      union { unsigned u; float f; } lo, hi;
      lo.u = pv[j] << 16;
      hi.u = pv[j] & 0xffff0000u;
      acc0 += wj * lo.f;
      acc1 += wj * hi.f;
    }
  }

  float inv = (wsum > 0.f) ? (1.0f / wsum) : 0.f;
  const size_t o = (size_t)n * 128 + 2 * lane;
  float2 xr = *(const float2*)&out[o];
  float2 res; res.x = acc0 * inv + xr.x; res.y = acc1 * inv + xr.y;
  *(float2*)&out[o] = res;
}

// ---------------------------------------------------------------------------
extern "C" void kernel_launch(void* const* d_in, const int* in_sizes, int n_in,
                              void* d_out, int out_size, void* d_ws, size_t ws_size,
                              hipStream_t stream) {
  const float* x    = (const float*)d_in[0];
  const int*   row  = (const int*)d_in[1];
  const int*   col  = (const int*)d_in[2];
  const float* Wl   = (const float*)d_in[3];
  const float* Wr   = (const float*)d_in[4];
  const float* a1w  = (const float*)d_in[5];
  const float* a2w  = (const float*)d_in[6];
  const float* bias = (const float*)d_in[7];
  float* out = (float*)d_out;
  const int N = in_sizes[0] / 128;
  const int E = in_sizes[1];
  (void)n_in; (void)out_size; (void)ws_size;

  const int NBK = (N + BK - 1) / BK;   // 782 for N=100K (<=1024 required)

  char* ws = (char*)d_ws;
  size_t off = 0;
  auto carve = [&](size_t bytes) { void* p = ws + off; off += (bytes + 255) & ~(size_t)255; return p; };
  char* xls            = (char*)carve((size_t)N * REC);                 // 25.6 MB, 256B-aligned
  float* s1            = (float*)carve((size_t)N * 4 * 4);
  float* s2            = (float*)carve((size_t)N * 4 * 4);              // 1.6 MB, L2-resident
  int* offs            = (int*)carve((size_t)N * 4);
  int* deg             = (int*)carve((size_t)N * 4);
  unsigned int* colsort= (unsigned int*)carve((size_t)NBK * CAPC * 4);  // 11.2 MB
  int* bcur            = (int*)carve((size_t)NBK * BSTR * 4);           // padded: 1/line
  unsigned short* Wtg  = (unsigned short*)carve((size_t)2 * 136 * 128 * 2);

  const int nb64       = (N + 63) / 64;
  const int gemmBlocks = 2 * nb64;                 // 3126 (y-split)
  const int binBlocks  = (E + EPB - 1) / EPB;      // 196
  const int S          = gemmBlocks / binBlocks + 1; // bin every S-th block
  const int T          = gemmBlocks + binBlocks;   // 3322

  wprep_k   <<<dim3(136, 2), 128, 0, stream>>>(Wl, Wr, a1w, a2w, Wtg, bcur, NBK);
  gemm_bin_k<<<T, 256, 0, stream>>>(x, Wtg, bias, xls, out, s1, s2, N,
                                    row, col, bcur, colsort, E, NBK,
                                    binBlocks, gemmBlocks, S);
  csr_k     <<<NBK, 256, 0, stream>>>(bcur, offs, deg, colsort, N);
  agg_k     <<<(N + 3) / 4, 256, 0, stream>>>(offs, deg, colsort, s1, s2, xls, out, N);
}

// Round 9
// 265.878 us; speedup vs baseline: 1.6760x; 1.6760x over previous
//
#include <hip/hip_runtime.h>

// GATConv on MI355X. Inputs fp32, indices int32, OUTPUT fp32.
// bf16 for MFMA GEMM inputs + xls workspace; fp32 accumulation everywhere.
// R16 = R6 structure (best fused: 269.7us) + exactly two counter-driven
// fixes. (R8's 3-change y-split rewrite regressed 2.5x unexplained ->
// reverted wholesale; minimal-diff discipline.)
//   FIX 1: x in REGISTERS (afx[4], per-lane contiguous 32B runs of its own
//     row, loaded once for both y passes). Kills xs staging pass + 1 sync;
//     LDS 52.2KB -> 32KB => 5 blocks/CU (occ cap 26%->62%).
//   FIX 2: Ws XOR-swizzled 16B groups (g ^= row&7, NO pad). The padded
//     [136] layout was an 8-way read conflict (stride 68 dw == 4 mod 32,
//     bank = 4(m+quad) mod 32) = R6's 2.17M conflict cycles. Swizzle hits
//     the 2-lanes/bank minimum (free).
// bin (EPB 2048, rloc[8], %3 interleave), csr (binned->ecache), agg, wprep:
// byte-identical to R6.

typedef short bfvec8 __attribute__((ext_vector_type(8)));  // 8 bf16 (4 VGPRs)
typedef float f32x4  __attribute__((ext_vector_type(4)));

#define BK 128      // nodes per bucket (bucket id = row >> 7)
#define CAPC 3584   // static bucket capacity (mean 2048, sd 45 -> +34 sigma)
#define EPB 2048    // edges per bin sub-block
#define REC 256     // xls record bytes: 128 bf16 x_l, 256B-aligned
#define BSTR 16     // bcur stride in ints: one counter per 64B line

__device__ __forceinline__ unsigned short f2bf(float f) {
  union { float f; unsigned int i; } v; v.f = f;
  unsigned int r = v.i + 0x7fffu + ((v.i >> 16) & 1u);  // RNE
  return (unsigned short)(r >> 16);
}

// ---------------------------------------------------------------------------
// Wt[y][n][k] bf16, n<128 -> W^T. y=0 rows 128..131 = a1w^T*log2e,
// 132..135 = a2w^T*log2e. Blocks (x<8, y=0) also init bcur (folded init_k).
__global__ __launch_bounds__(128) void wprep_k(
    const float* __restrict__ Wl, const float* __restrict__ Wr,
    const float* __restrict__ a1w, const float* __restrict__ a2w,
    unsigned short* __restrict__ Wtg, int* __restrict__ bcur, int NBK)
{
  const int n = blockIdx.x;      // 0..135
  const int y = blockIdx.y;      // 0..1
  const int k = threadIdx.x;     // 0..127
  if (y == 0 && n < 8) {
    int b = n * 128 + k;
    if (b < NBK) bcur[b * BSTR] = b * CAPC;
  }
  const float* W = y ? Wr : Wl;
  const float LOG2E = 1.4426950408889634f;
  float v;
  if (n < 128)      v = W[(size_t)k * 128 + n];
  else if (y)       v = 0.f;                                  // unused
  else if (n < 132) v = a1w[k * 4 + (n - 128)] * LOG2E;
  else              v = a2w[k * 4 + (n - 132)] * LOG2E;
  Wtg[((size_t)y * 136 + n) * 128 + k] = f2bf(v);
}

// ---------------------------------------------------------------------------
// FUSED kernel: role-split blocks (bid%3==0 -> bin, interleaved).
//   role GEMM: 64 x-rows, both y passes. x-fragments in regs (afx[4], one
//     load); W staged per-y into XOR-swizzled LDS [128][128] (32KB, no pad,
//     conflict-free reads); a-tile rows (y=0) in regs from L2-hot global.
//     SWAPPED MFMA (D^T): lane (m,quad) owns one x-row, 4 consecutive
//     out-cols per n-tile -> vectorized stores.
//     y=0: xls = x@W_l (bf16), s1 = x@a1w', s2 = x@a2w'; y=1: out=x@W_r+bias.
//   role BIN: ticketed binning of EPB edges. LDS hist -> ONE global atomic
//     per (block, nonempty bucket) -> LDS-ranked scatter into binned.
//     Entry packed 4B: (r&127)<<17 | c  (c < 2^17).
__global__ __launch_bounds__(256) void gemm_bin_k(
    const float* __restrict__ x, const unsigned short* __restrict__ Wtg,
    const float* __restrict__ bias,
    char* __restrict__ xls, float* __restrict__ out,
    float* __restrict__ s1, float* __restrict__ s2, int N,
    const int* __restrict__ row, const int* __restrict__ col,
    int* __restrict__ bcur, unsigned int* __restrict__ binned,
    int E, int NBK, int binBlocks, int gemmBlocks)
{
  __shared__ __align__(16) char raw[32768];   // gemm: Ws[128][128]; bin: h/base
  const int bid = blockIdx.x;
  const int t = threadIdx.x;
  const bool isbin = (bid % 3 == 0) && (bid / 3 < binBlocks);

  if (isbin) {
    // ---------------- BIN role ----------------
    int* h    = (int*)raw;            // [NBK] counts / cursors
    int* base = (int*)(raw + 4096);   // [NBK] global bases
    const int sub = bid / 3;
    const int e0 = sub * EPB;
    const int e1 = min(e0 + EPB, E);

    int rloc[8];
    for (int i = t; i < NBK; i += 256) h[i] = 0;
    __syncthreads();
    #pragma unroll
    for (int k = 0; k < 8; ++k) {
      int e = e0 + t + (k << 8);
      rloc[k] = (e < e1) ? row[e] : -1;
      if (rloc[k] >= 0) atomicAdd(&h[rloc[k] >> 7], 1);
    }
    __syncthreads();
    for (int i = t; i < NBK; i += 256) {
      int c = h[i];
      base[i] = c ? atomicAdd(&bcur[i * BSTR], c) : 0;
    }
    __syncthreads();
    for (int i = t; i < NBK; i += 256) h[i] = 0;   // reuse as local cursor
    __syncthreads();
    #pragma unroll
    for (int k = 0; k < 8; ++k) {
      int e = e0 + t + (k << 8);
      if (e < e1) {
        int r = rloc[k];
        unsigned c = (unsigned)col[e];
        int b = r >> 7;
        int rk = atomicAdd(&h[b], 1);
        binned[base[b] + rk] = ((unsigned)(r & 127) << 17) | c;
      }
    }
    return;
  }

  // ---------------- GEMM role ----------------
  unsigned short* Ws = (unsigned short*)raw;   // [128][128], XOR-swizzled 16B groups
  const int sub = bid - min(bid / 3 + 1, binBlocks);
  if (sub >= gemmBlocks) return;
  const int n0 = sub * 64;

  const int w    = t >> 6;
  const int lane = t & 63;
  const int m    = lane & 15;
  const int m7   = m & 7;
  const int quad = lane >> 4;
  const int nrow = n0 + 16 * w + m;   // this lane's single output row
  const int kb   = quad * 8;          // k-offset within each 32-wide chunk

  // x fragments: 8 fp32 -> bf16x8 per k-chunk, loaded ONCE, reused both y.
  bfvec8 afx[4];
  #pragma unroll
  for (int kc4 = 0; kc4 < 4; ++kc4) {
    f32x4 u = (f32x4){0.f, 0.f, 0.f, 0.f};
    f32x4 v = (f32x4){0.f, 0.f, 0.f, 0.f};
    if (nrow < N) {
      const float* xp = &x[(size_t)nrow * 128 + kc4 * 32 + kb];
      u = *(const f32x4*)xp;
      v = *(const f32x4*)(xp + 4);
    }
    bfvec8 a;
    a[0] = (short)f2bf(u[0]); a[1] = (short)f2bf(u[1]);
    a[2] = (short)f2bf(u[2]); a[3] = (short)f2bf(u[3]);
    a[4] = (short)f2bf(v[0]); a[5] = (short)f2bf(v[1]);
    a[6] = (short)f2bf(v[2]); a[7] = (short)f2bf(v[3]);
    afx[kc4] = a;
  }

  // a-tile rows (y=0 extra tile) straight from L2-hot global into regs
  bfvec8 ar[4];
  {
    int arow = 128 + (m < 8 ? m : 7);
    #pragma unroll
    for (int kc4 = 0; kc4 < 4; ++kc4)
      ar[kc4] = *(const bfvec8*)&Wtg[(size_t)arow * 128 + kc4 * 32 + kb];
  }

  #pragma unroll
  for (int y = 0; y < 2; ++y) {
    const unsigned short* Wt = Wtg + (size_t)y * 136 * 128;
    if (y) __syncthreads();          // all waves done reading Ws of y=0
    // cooperative W stage: group g of row nr lands at g ^ (nr&7)
    for (int i = t; i < 2048; i += 256) {
      int nr = i >> 4, g = i & 15;
      int gs = (g ^ (nr & 7)) << 3;
      *(uint4*)&Ws[nr * 128 + gs] = *(const uint4*)&Wt[(size_t)nr * 128 + (g << 3)];
    }
    __syncthreads();

    f32x4 acc[9];
    #pragma unroll
    for (int i = 0; i < 9; ++i) acc[i] = (f32x4){0.f, 0.f, 0.f, 0.f};

    #pragma unroll
    for (int kc4 = 0; kc4 < 4; ++kc4) {
      #pragma unroll
      for (int nt = 0; nt < 8; ++nt) {
        int g = kc4 * 4 + quad;                  // logical 16B group
        bfvec8 bfr = *(const bfvec8*)&Ws[(nt * 16 + m) * 128 + ((g ^ m7) << 3)];
        acc[nt] = __builtin_amdgcn_mfma_f32_16x16x32_bf16(bfr, afx[kc4], acc[nt], 0, 0, 0);
      }
      if (y == 0)
        acc[8] = __builtin_amdgcn_mfma_f32_16x16x32_bf16(ar[kc4], afx[kc4], acc[8], 0, 0, 0);
    }

    if (nrow < N) {
      if (y) {
        #pragma unroll
        for (int nt = 0; nt < 8; ++nt) {
          int c = nt * 16 + quad * 4;
          float4 b4 = *(const float4*)&bias[c];
          float4 v = make_float4(acc[nt][0] + b4.x, acc[nt][1] + b4.y,
                                 acc[nt][2] + b4.z, acc[nt][3] + b4.w);
          *(float4*)&out[(size_t)nrow * 128 + c] = v;
        }
      } else {
        #pragma unroll
        for (int nt = 0; nt < 8; ++nt) {
          int c = nt * 16 + quad * 4;
          unsigned lo = (unsigned)f2bf(acc[nt][0]) | ((unsigned)f2bf(acc[nt][1]) << 16);
          unsigned hi = (unsigned)f2bf(acc[nt][2]) | ((unsigned)f2bf(acc[nt][3]) << 16);
          *(uint2*)(xls + ((size_t)nrow << 8) + 2 * c) = make_uint2(lo, hi);
        }
        if (quad == 0) *(f32x4*)&s1[nrow * 4] = acc[8];      // a-cols 0..3
        else if (quad == 1) *(f32x4*)&s2[nrow * 4] = acc[8]; // a-cols 4..7
      }
    }
  }
}

// ---------------------------------------------------------------------------
// Block b owns bucket b (128 nodes): binned cached in LDS during hist (ONE
// global read), LDS scan (first-128 threads) -> offs/deg; LDS-cursor scatter
// of PREMULTIPLIED cols (c<<8) into colsort window.
__global__ __launch_bounds__(256) void csr_k(const unsigned int* __restrict__ binned,
    const int* __restrict__ bcur, int* __restrict__ offs, int* __restrict__ deg,
    unsigned int* __restrict__ colsort, int N)
{
  __shared__ unsigned ecache[CAPC];   // 14.3KB
  __shared__ int h[BK];
  __shared__ int sh[BK];
  const int t = threadIdx.x;
  const int b = blockIdx.x;
  const int lo = b * BK;
  const int e0 = b * CAPC;
  const int e1 = bcur[b * BSTR];   // e0 + cnt

  if (t < BK) h[t] = 0;
  __syncthreads();
  for (int i = e0 + t; i < e1; i += 256) {
    unsigned p = binned[i];
    ecache[i - e0] = p;
    atomicAdd(&h[p >> 17], 1);
  }
  __syncthreads();

  int v = 0;
  if (t < BK) { v = h[t]; sh[t] = v; }
  __syncthreads();
  for (int off = 1; off < BK; off <<= 1) {
    int tv = (t < BK && t >= off) ? sh[t - off] : 0;
    __syncthreads();
    if (t < BK) sh[t] += tv;
    __syncthreads();
  }
  if (t < BK) {
    int ex = sh[t] - v;
    int node = lo + t;
    if (node < N) { offs[node] = e0 + ex; deg[node] = v; }
    h[t] = ex;          // reuse as cursor
  }
  __syncthreads();
  const int cnt = e1 - e0;
  for (int i = t; i < cnt; i += 256) {
    unsigned p = ecache[i];
    int rlo = p >> 17;
    unsigned c = p & 0x1FFFFu;
    int pos = atomicAdd(&h[rlo], 1);
    colsort[e0 + pos] = c << 8;    // premultiplied byte base (REC=256)
  }
}

// ---------------------------------------------------------------------------
// One wave per node. Lane l: dims {2l,2l+1}, head l>>4.
// 8-chunks, softmax de-duplicated: lanes compute wv = exp2(leaky(s1+s2)) for
// (edge (l>>2)&7, head l&3) -- ONE v_exp_f32 per chunk -- then 8 shfl
// broadcast wv[j] to accumulation lanes. Tail: ONE masked chunk.
__global__ __launch_bounds__(256) void agg_k(const int* __restrict__ offs,
    const int* __restrict__ deg, const unsigned int* __restrict__ colsort,
    const float* __restrict__ s1, const float* __restrict__ s2,
    const char* __restrict__ xls, float* __restrict__ out, int N)
{
  const int lane = threadIdx.x & 63;
  const int n = blockIdx.x * 4 + (threadIdx.x >> 6);
  if (n >= N) return;
  const int e0 = offs[n], e1 = e0 + deg[n];
  const int h  = lane >> 4;          // accumulation head
  const int hp = lane & 3;           // softmax head
  const int jj = (lane >> 2) & 7;    // softmax edge slot
  const float s1c = s1[n * 4 + hp];                // pre-scaled by log2e
  const unsigned lane4 = (unsigned)(lane << 2);
  const unsigned hp4   = (unsigned)(hp << 2);
  const char* s2b = (const char*)s2;

  float acc0 = 0.f, acc1 = 0.f, wsum = 0.f;
  int i0 = e0;
  for (; i0 + 8 <= e1; i0 += 8) {
    // softmax phase: 32 (edge,head) pairs across lanes (upper half mirrors)
    unsigned csl = colsort[i0 + jj];                       // 8 distinct addrs
    float z2 = *(const float*)(s2b + ((csl >> 4) + hp4));  // L2-resident table
    float z = s1c + z2;
    z = fmaxf(z, 0.2f * z);                                // leaky (pos scale ok)
    float wv = exp2f(z);                                   // ONE v_exp_f32

    // gather phase: 256B-aligned records, 8 independent loads in flight
    unsigned cs[8];
    #pragma unroll
    for (int j = 0; j < 8; ++j) cs[j] = colsort[i0 + j];   // broadcast
    unsigned pv[8];
    #pragma unroll
    for (int j = 0; j < 8; ++j)
      pv[j] = *(const unsigned*)(xls + (cs[j] + lane4));

    // broadcast + accumulate
    #pragma unroll
    for (int j = 0; j < 8; ++j) {
      float wj = __shfl(wv, (j << 2) | h);                 // ds_bpermute
      wsum += wj;
      union { unsigned u; float f; } lo, hi;
      lo.u = pv[j] << 16;
      hi.u = pv[j] & 0xffff0000u;
      acc0 += wj * lo.f;
      acc1 += wj * hi.f;
    }
  }
  if (i0 < e1) {                     // masked parallel tail chunk (rem 1..7)
    const int rem = e1 - i0;
    unsigned csl = colsort[i0 + (jj < rem ? jj : rem - 1)];
    float z2 = *(const float*)(s2b + ((csl >> 4) + hp4));
    float z = s1c + z2;
    z = fmaxf(z, 0.2f * z);
    float wv = (jj < rem) ? exp2f(z) : 0.f;

    unsigned cs[8];
    #pragma unroll
    for (int j = 0; j < 8; ++j) cs[j] = colsort[i0 + (j < rem ? j : rem - 1)];
    unsigned pv[8];
    #pragma unroll
    for (int j = 0; j < 8; ++j)
      pv[j] = *(const unsigned*)(xls + (cs[j] + lane4));

    #pragma unroll
    for (int j = 0; j < 8; ++j) {
      float wj = __shfl(wv, (j << 2) | h);                 // 0 for j>=rem
      wsum += wj;
      union { unsigned u; float f; } lo, hi;
      lo.u = pv[j] << 16;
      hi.u = pv[j] & 0xffff0000u;
      acc0 += wj * lo.f;
      acc1 += wj * hi.f;
    }
  }

  float inv = (wsum > 0.f) ? (1.0f / wsum) : 0.f;
  const size_t o = (size_t)n * 128 + 2 * lane;
  float2 xr = *(const float2*)&out[o];
  float2 res; res.x = acc0 * inv + xr.x; res.y = acc1 * inv + xr.y;
  *(float2*)&out[o] = res;
}

// ---------------------------------------------------------------------------
extern "C" void kernel_launch(void* const* d_in, const int* in_sizes, int n_in,
                              void* d_out, int out_size, void* d_ws, size_t ws_size,
                              hipStream_t stream) {
  const float* x    = (const float*)d_in[0];
  const int*   row  = (const int*)d_in[1];
  const int*   col  = (const int*)d_in[2];
  const float* Wl   = (const float*)d_in[3];
  const float* Wr   = (const float*)d_in[4];
  const float* a1w  = (const float*)d_in[5];
  const float* a2w  = (const float*)d_in[6];
  const float* bias = (const float*)d_in[7];
  float* out = (float*)d_out;
  const int N = in_sizes[0] / 128;
  const int E = in_sizes[1];
  (void)n_in; (void)out_size; (void)ws_size;

  const int NBK = (N + BK - 1) / BK;   // 782 for N=100K (<=1024 required)

  char* ws = (char*)d_ws;
  size_t off = 0;
  auto carve = [&](size_t bytes) { void* p = ws + off; off += (bytes + 255) & ~(size_t)255; return p; };
  char* xls            = (char*)carve((size_t)N * REC);                 // 25.6 MB, 256B-aligned
  float* s1            = (float*)carve((size_t)N * 4 * 4);
  float* s2            = (float*)carve((size_t)N * 4 * 4);              // 1.6 MB, L2-resident
  int* offs            = (int*)carve((size_t)N * 4);
  int* deg             = (int*)carve((size_t)N * 4);
  unsigned int* colsort= (unsigned int*)carve((size_t)NBK * CAPC * 4);  // 11.2 MB
  unsigned int* binned = (unsigned int*)carve((size_t)NBK * CAPC * 4);  // 11.2 MB
  int* bcur            = (int*)carve((size_t)NBK * BSTR * 4);           // padded: 1/line
  unsigned short* Wtg  = (unsigned short*)carve((size_t)2 * 136 * 128 * 2);

  const int gemmBlocks = (N + 63) / 64;          // 1563
  const int binBlocks  = (E + EPB - 1) / EPB;    // 782
  const int T = gemmBlocks + binBlocks;          // 2345

  wprep_k   <<<dim3(136, 2), 128, 0, stream>>>(Wl, Wr, a1w, a2w, Wtg, bcur, NBK);
  gemm_bin_k<<<T, 256, 0, stream>>>(x, Wtg, bias, xls, out, s1, s2, N,
                                    row, col, bcur, binned, E, NBK,
                                    binBlocks, gemmBlocks);
  csr_k     <<<NBK, 256, 0, stream>>>(binned, bcur, offs, deg, colsort, N);
  agg_k     <<<(N + 3) / 4, 256, 0, stream>>>(offs, deg, colsort, s1, s2, xls, out, N);
}

// Round 10
// 256.820 us; speedup vs baseline: 1.7351x; 1.0353x over previous
//
#include <hip/hip_runtime.h>

// GATConv on MI355X. Inputs fp32, indices int32, OUTPUT fp32.
// bf16 for MFMA GEMM inputs + xls workspace; fp32 accumulation everywhere.
// R17 = R9 + ONE change: EPB 2048 -> 8192. R9 counters killed the
// bank-conflict theory (swizzle: 2.17M->1.97M, = inherent b128 8/bank,
// 0.004% of cycles) and the LDS-occupancy theory (32KB yet occ ~25%).
// Remaining suspect: bin ticket atomics -- EPB=2048 meant 782 blocks x
// ~720 nonempty buckets = 563K line-contended global atomics (~720-deep
// queue per bcur line). EPB=8192: 196 x ~782 = 153K, 196-deep (~4us).
// Bin role: 32 edges/thread in rloc[32] (VGPR-proven in R8's bin).
// gemm role / csr / agg / wprep: byte-identical to R9.

typedef short bfvec8 __attribute__((ext_vector_type(8)));  // 8 bf16 (4 VGPRs)
typedef float f32x4  __attribute__((ext_vector_type(4)));

#define BK 128      // nodes per bucket (bucket id = row >> 7)
#define CAPC 3584   // static bucket capacity (mean 2048, sd 45 -> +34 sigma)
#define EPB 8192    // edges per bin sub-block
#define REC 256     // xls record bytes: 128 bf16 x_l, 256B-aligned
#define BSTR 16     // bcur stride in ints: one counter per 64B line

__device__ __forceinline__ unsigned short f2bf(float f) {
  union { float f; unsigned int i; } v; v.f = f;
  unsigned int r = v.i + 0x7fffu + ((v.i >> 16) & 1u);  // RNE
  return (unsigned short)(r >> 16);
}

// ---------------------------------------------------------------------------
// Wt[y][n][k] bf16, n<128 -> W^T. y=0 rows 128..131 = a1w^T*log2e,
// 132..135 = a2w^T*log2e. Blocks (x<8, y=0) also init bcur (folded init_k).
__global__ __launch_bounds__(128) void wprep_k(
    const float* __restrict__ Wl, const float* __restrict__ Wr,
    const float* __restrict__ a1w, const float* __restrict__ a2w,
    unsigned short* __restrict__ Wtg, int* __restrict__ bcur, int NBK)
{
  const int n = blockIdx.x;      // 0..135
  const int y = blockIdx.y;      // 0..1
  const int k = threadIdx.x;     // 0..127
  if (y == 0 && n < 8) {
    int b = n * 128 + k;
    if (b < NBK) bcur[b * BSTR] = b * CAPC;
  }
  const float* W = y ? Wr : Wl;
  const float LOG2E = 1.4426950408889634f;
  float v;
  if (n < 128)      v = W[(size_t)k * 128 + n];
  else if (y)       v = 0.f;                                  // unused
  else if (n < 132) v = a1w[k * 4 + (n - 128)] * LOG2E;
  else              v = a2w[k * 4 + (n - 132)] * LOG2E;
  Wtg[((size_t)y * 136 + n) * 128 + k] = f2bf(v);
}

// ---------------------------------------------------------------------------
// FUSED kernel: role-split blocks (bid%3==0 -> bin, first 196 slots).
//   role GEMM: 64 x-rows, both y passes. x-fragments in regs (afx[4], one
//     load); W staged per-y into XOR-swizzled LDS [128][128] (32KB);
//     a-tile rows (y=0) in regs from L2-hot global.
//     SWAPPED MFMA (D^T): lane (m,quad) owns one x-row, 4 consecutive
//     out-cols per n-tile -> vectorized stores.
//     y=0: xls = x@W_l (bf16), s1 = x@a1w', s2 = x@a2w'; y=1: out=x@W_r+bias.
//   role BIN: ticketed binning of EPB=8192 edges (32/thread in rloc[32]).
//     LDS hist -> ONE global atomic per (block, nonempty bucket) ->
//     LDS-ranked scatter into binned. Entry packed: (r&127)<<17 | c.
__global__ __launch_bounds__(256) void gemm_bin_k(
    const float* __restrict__ x, const unsigned short* __restrict__ Wtg,
    const float* __restrict__ bias,
    char* __restrict__ xls, float* __restrict__ out,
    float* __restrict__ s1, float* __restrict__ s2, int N,
    const int* __restrict__ row, const int* __restrict__ col,
    int* __restrict__ bcur, unsigned int* __restrict__ binned,
    int E, int NBK, int binBlocks, int gemmBlocks)
{
  __shared__ __align__(16) char raw[32768];   // gemm: Ws[128][128]; bin: h/base
  const int bid = blockIdx.x;
  const int t = threadIdx.x;
  const bool isbin = (bid % 3 == 0) && (bid / 3 < binBlocks);

  if (isbin) {
    // ---------------- BIN role ----------------
    int* h    = (int*)raw;            // [NBK] counts / cursors
    int* base = (int*)(raw + 4096);   // [NBK] global bases
    const int sub = bid / 3;
    const int e0 = sub * EPB;
    const int e1 = min(e0 + EPB, E);

    int rloc[32];
    for (int i = t; i < NBK; i += 256) h[i] = 0;
    __syncthreads();
    #pragma unroll
    for (int k = 0; k < 32; ++k) {
      int e = e0 + t + (k << 8);
      rloc[k] = (e < e1) ? row[e] : -1;
      if (rloc[k] >= 0) atomicAdd(&h[rloc[k] >> 7], 1);
    }
    __syncthreads();
    for (int i = t; i < NBK; i += 256) {
      int c = h[i];
      base[i] = c ? atomicAdd(&bcur[i * BSTR], c) : 0;
    }
    __syncthreads();
    for (int i = t; i < NBK; i += 256) h[i] = 0;   // reuse as local cursor
    __syncthreads();
    #pragma unroll
    for (int k = 0; k < 32; ++k) {
      int e = e0 + t + (k << 8);
      if (e < e1) {
        int r = rloc[k];
        unsigned c = (unsigned)col[e];
        int b = r >> 7;
        int rk = atomicAdd(&h[b], 1);
        binned[base[b] + rk] = ((unsigned)(r & 127) << 17) | c;
      }
    }
    return;
  }

  // ---------------- GEMM role ----------------
  unsigned short* Ws = (unsigned short*)raw;   // [128][128], XOR-swizzled 16B groups
  const int sub = bid - min(bid / 3 + 1, binBlocks);
  if (sub >= gemmBlocks) return;
  const int n0 = sub * 64;

  const int w    = t >> 6;
  const int lane = t & 63;
  const int m    = lane & 15;
  const int m7   = m & 7;
  const int quad = lane >> 4;
  const int nrow = n0 + 16 * w + m;   // this lane's single output row
  const int kb   = quad * 8;          // k-offset within each 32-wide chunk

  // x fragments: 8 fp32 -> bf16x8 per k-chunk, loaded ONCE, reused both y.
  bfvec8 afx[4];
  #pragma unroll
  for (int kc4 = 0; kc4 < 4; ++kc4) {
    f32x4 u = (f32x4){0.f, 0.f, 0.f, 0.f};
    f32x4 v = (f32x4){0.f, 0.f, 0.f, 0.f};
    if (nrow < N) {
      const float* xp = &x[(size_t)nrow * 128 + kc4 * 32 + kb];
      u = *(const f32x4*)xp;
      v = *(const f32x4*)(xp + 4);
    }
    bfvec8 a;
    a[0] = (short)f2bf(u[0]); a[1] = (short)f2bf(u[1]);
    a[2] = (short)f2bf(u[2]); a[3] = (short)f2bf(u[3]);
    a[4] = (short)f2bf(v[0]); a[5] = (short)f2bf(v[1]);
    a[6] = (short)f2bf(v[2]); a[7] = (short)f2bf(v[3]);
    afx[kc4] = a;
  }

  // a-tile rows (y=0 extra tile) straight from L2-hot global into regs
  bfvec8 ar[4];
  {
    int arow = 128 + (m < 8 ? m : 7);
    #pragma unroll
    for (int kc4 = 0; kc4 < 4; ++kc4)
      ar[kc4] = *(const bfvec8*)&Wtg[(size_t)arow * 128 + kc4 * 32 + kb];
  }

  #pragma unroll
  for (int y = 0; y < 2; ++y) {
    const unsigned short* Wt = Wtg + (size_t)y * 136 * 128;
    if (y) __syncthreads();          // all waves done reading Ws of y=0
    // cooperative W stage: group g of row nr lands at g ^ (nr&7)
    for (int i = t; i < 2048; i += 256) {
      int nr = i >> 4, g = i & 15;
      int gs = (g ^ (nr & 7)) << 3;
      *(uint4*)&Ws[nr * 128 + gs] = *(const uint4*)&Wt[(size_t)nr * 128 + (g << 3)];
    }
    __syncthreads();

    f32x4 acc[9];
    #pragma unroll
    for (int i = 0; i < 9; ++i) acc[i] = (f32x4){0.f, 0.f, 0.f, 0.f};

    #pragma unroll
    for (int kc4 = 0; kc4 < 4; ++kc4) {
      #pragma unroll
      for (int nt = 0; nt < 8; ++nt) {
        int g = kc4 * 4 + quad;                  // logical 16B group
        bfvec8 bfr = *(const bfvec8*)&Ws[(nt * 16 + m) * 128 + ((g ^ m7) << 3)];
        acc[nt] = __builtin_amdgcn_mfma_f32_16x16x32_bf16(bfr, afx[kc4], acc[nt], 0, 0, 0);
      }
      if (y == 0)
        acc[8] = __builtin_amdgcn_mfma_f32_16x16x32_bf16(ar[kc4], afx[kc4], acc[8], 0, 0, 0);
    }

    if (nrow < N) {
      if (y) {
        #pragma unroll
        for (int nt = 0; nt < 8; ++nt) {
          int c = nt * 16 + quad * 4;
          float4 b4 = *(const float4*)&bias[c];
          float4 v = make_float4(acc[nt][0] + b4.x, acc[nt][1] + b4.y,
                                 acc[nt][2] + b4.z, acc[nt][3] + b4.w);
          *(float4*)&out[(size_t)nrow * 128 + c] = v;
        }
      } else {
        #pragma unroll
        for (int nt = 0; nt < 8; ++nt) {
          int c = nt * 16 + quad * 4;
          unsigned lo = (unsigned)f2bf(acc[nt][0]) | ((unsigned)f2bf(acc[nt][1]) << 16);
          unsigned hi = (unsigned)f2bf(acc[nt][2]) | ((unsigned)f2bf(acc[nt][3]) << 16);
          *(uint2*)(xls + ((size_t)nrow << 8) + 2 * c) = make_uint2(lo, hi);
        }
        if (quad == 0) *(f32x4*)&s1[nrow * 4] = acc[8];      // a-cols 0..3
        else if (quad == 1) *(f32x4*)&s2[nrow * 4] = acc[8]; // a-cols 4..7
      }
    }
  }
}

// ---------------------------------------------------------------------------
// Block b owns bucket b (128 nodes): binned cached in LDS during hist (ONE
// global read), LDS scan (first-128 threads) -> offs/deg; LDS-cursor scatter
// of PREMULTIPLIED cols (c<<8) into colsort window.
__global__ __launch_bounds__(256) void csr_k(const unsigned int* __restrict__ binned,
    const int* __restrict__ bcur, int* __restrict__ offs, int* __restrict__ deg,
    unsigned int* __restrict__ colsort, int N)
{
  __shared__ unsigned ecache[CAPC];   // 14.3KB
  __shared__ int h[BK];
  __shared__ int sh[BK];
  const int t = threadIdx.x;
  const int b = blockIdx.x;
  const int lo = b * BK;
  const int e0 = b * CAPC;
  const int e1 = bcur[b * BSTR];   // e0 + cnt

  if (t < BK) h[t] = 0;
  __syncthreads();
  for (int i = e0 + t; i < e1; i += 256) {
    unsigned p = binned[i];
    ecache[i - e0] = p;
    atomicAdd(&h[p >> 17], 1);
  }
  __syncthreads();

  int v = 0;
  if (t < BK) { v = h[t]; sh[t] = v; }
  __syncthreads();
  for (int off = 1; off < BK; off <<= 1) {
    int tv = (t < BK && t >= off) ? sh[t - off] : 0;
    __syncthreads();
    if (t < BK) sh[t] += tv;
    __syncthreads();
  }
  if (t < BK) {
    int ex = sh[t] - v;
    int node = lo + t;
    if (node < N) { offs[node] = e0 + ex; deg[node] = v; }
    h[t] = ex;          // reuse as cursor
  }
  __syncthreads();
  const int cnt = e1 - e0;
  for (int i = t; i < cnt; i += 256) {
    unsigned p = ecache[i];
    int rlo = p >> 17;
    unsigned c = p & 0x1FFFFu;
    int pos = atomicAdd(&h[rlo], 1);
    colsort[e0 + pos] = c << 8;    // premultiplied byte base (REC=256)
  }
}

// ---------------------------------------------------------------------------
// One wave per node. Lane l: dims {2l,2l+1}, head l>>4.
// 8-chunks, softmax de-duplicated: lanes compute wv = exp2(leaky(s1+s2)) for
// (edge (l>>2)&7, head l&3) -- ONE v_exp_f32 per chunk -- then 8 shfl
// broadcast wv[j] to accumulation lanes. Tail: ONE masked chunk.
__global__ __launch_bounds__(256) void agg_k(const int* __restrict__ offs,
    const int* __restrict__ deg, const unsigned int* __restrict__ colsort,
    const float* __restrict__ s1, const float* __restrict__ s2,
    const char* __restrict__ xls, float* __restrict__ out, int N)
{
  const int lane = threadIdx.x & 63;
  const int n = blockIdx.x * 4 + (threadIdx.x >> 6);
  if (n >= N) return;
  const int e0 = offs[n], e1 = e0 + deg[n];
  const int h  = lane >> 4;          // accumulation head
  const int hp = lane & 3;           // softmax head
  const int jj = (lane >> 2) & 7;    // softmax edge slot
  const float s1c = s1[n * 4 + hp];                // pre-scaled by log2e
  const unsigned lane4 = (unsigned)(lane << 2);
  const unsigned hp4   = (unsigned)(hp << 2);
  const char* s2b = (const char*)s2;

  float acc0 = 0.f, acc1 = 0.f, wsum = 0.f;
  int i0 = e0;
  for (; i0 + 8 <= e1; i0 += 8) {
    // softmax phase: 32 (edge,head) pairs across lanes (upper half mirrors)
    unsigned csl = colsort[i0 + jj];                       // 8 distinct addrs
    float z2 = *(const float*)(s2b + ((csl >> 4) + hp4));  // L2-resident table
    float z = s1c + z2;
    z = fmaxf(z, 0.2f * z);                                // leaky (pos scale ok)
    float wv = exp2f(z);                                   // ONE v_exp_f32

    // gather phase: 256B-aligned records, 8 independent loads in flight
    unsigned cs[8];
    #pragma unroll
    for (int j = 0; j < 8; ++j) cs[j] = colsort[i0 + j];   // broadcast
    unsigned pv[8];
    #pragma unroll
    for (int j = 0; j < 8; ++j)
      pv[j] = *(const unsigned*)(xls + (cs[j] + lane4));

    // broadcast + accumulate
    #pragma unroll
    for (int j = 0; j < 8; ++j) {
      float wj = __shfl(wv, (j << 2) | h);                 // ds_bpermute
      wsum += wj;
      union { unsigned u; float f; } lo, hi;
      lo.u = pv[j] << 16;
      hi.u = pv[j] & 0xffff0000u;
      acc0 += wj * lo.f;
      acc1 += wj * hi.f;
    }
  }
  if (i0 < e1) {                     // masked parallel tail chunk (rem 1..7)
    const int rem = e1 - i0;
    unsigned csl = colsort[i0 + (jj < rem ? jj : rem - 1)];
    float z2 = *(const float*)(s2b + ((csl >> 4) + hp4));
    float z = s1c + z2;
    z = fmaxf(z, 0.2f * z);
    float wv = (jj < rem) ? exp2f(z) : 0.f;

    unsigned cs[8];
    #pragma unroll
    for (int j = 0; j < 8; ++j) cs[j] = colsort[i0 + (j < rem ? j : rem - 1)];
    unsigned pv[8];
    #pragma unroll
    for (int j = 0; j < 8; ++j)
      pv[j] = *(const unsigned*)(xls + (cs[j] + lane4));

    #pragma unroll
    for (int j = 0; j < 8; ++j) {
      float wj = __shfl(wv, (j << 2) | h);                 // 0 for j>=rem
      wsum += wj;
      union { unsigned u; float f; } lo, hi;
      lo.u = pv[j] << 16;
      hi.u = pv[j] & 0xffff0000u;
      acc0 += wj * lo.f;
      acc1 += wj * hi.f;
    }
  }

  float inv = (wsum > 0.f) ? (1.0f / wsum) : 0.f;
  const size_t o = (size_t)n * 128 + 2 * lane;
  float2 xr = *(const float2*)&out[o];
  float2 res; res.x = acc0 * inv + xr.x; res.y = acc1 * inv + xr.y;
  *(float2*)&out[o] = res;
}

// ---------------------------------------------------------------------------
extern "C" void kernel_launch(void* const* d_in, const int* in_sizes, int n_in,
                              void* d_out, int out_size, void* d_ws, size_t ws_size,
                              hipStream_t stream) {
  const float* x    = (const float*)d_in[0];
  const int*   row  = (const int*)d_in[1];
  const int*   col  = (const int*)d_in[2];
  const float* Wl   = (const float*)d_in[3];
  const float* Wr   = (const float*)d_in[4];
  const float* a1w  = (const float*)d_in[5];
  const float* a2w  = (const float*)d_in[6];
  const float* bias = (const float*)d_in[7];
  float* out = (float*)d_out;
  const int N = in_sizes[0] / 128;
  const int E = in_sizes[1];
  (void)n_in; (void)out_size; (void)ws_size;

  const int NBK = (N + BK - 1) / BK;   // 782 for N=100K (<=1024 required)

  char* ws = (char*)d_ws;
  size_t off = 0;
  auto carve = [&](size_t bytes) { void* p = ws + off; off += (bytes + 255) & ~(size_t)255; return p; };
  char* xls            = (char*)carve((size_t)N * REC);                 // 25.6 MB, 256B-aligned
  float* s1            = (float*)carve((size_t)N * 4 * 4);
  float* s2            = (float*)carve((size_t)N * 4 * 4);              // 1.6 MB, L2-resident
  int* offs            = (int*)carve((size_t)N * 4);
  int* deg             = (int*)carve((size_t)N * 4);
  unsigned int* colsort= (unsigned int*)carve((size_t)NBK * CAPC * 4);  // 11.2 MB
  unsigned int* binned = (unsigned int*)carve((size_t)NBK * CAPC * 4);  // 11.2 MB
  int* bcur            = (int*)carve((size_t)NBK * BSTR * 4);           // padded: 1/line
  unsigned short* Wtg  = (unsigned short*)carve((size_t)2 * 136 * 128 * 2);

  const int gemmBlocks = (N + 63) / 64;          // 1563
  const int binBlocks  = (E + EPB - 1) / EPB;    // 196
  const int T = gemmBlocks + binBlocks;          // 1759

  wprep_k   <<<dim3(136, 2), 128, 0, stream>>>(Wl, Wr, a1w, a2w, Wtg, bcur, NBK);
  gemm_bin_k<<<T, 256, 0, stream>>>(x, Wtg, bias, xls, out, s1, s2, N,
                                    row, col, bcur, binned, E, NBK,
                                    binBlocks, gemmBlocks);
  csr_k     <<<NBK, 256, 0, stream>>>(binned, bcur, offs, deg, colsort, N);
  agg_k     <<<(N + 3) / 4, 256, 0, stream>>>(offs, deg, colsort, s1, s2, xls, out, N);
}

// Round 11
// 255.981 us; speedup vs baseline: 1.7408x; 1.0033x over previous
//
#include <hip/hip_runtime.h>

// GATConv on MI355X. Inputs fp32, indices int32, OUTPUT fp32.
// bf16 for MFMA GEMM inputs + xls workspace; fp32 accumulation everywhere.
// R18 = R10 + ONE structural change: csr_k FUSED INTO agg_k (csragg_k,
// 782 blocks x 1024 thr). The bucket sort's output was only ever consumed
// bucket-locally -> sort into LDS (scol) and aggregate the bucket's 128
// nodes straight from it. Eliminates: csr kernel (~20us serial pipeline),
// 11MB colsort writes + 6.4MB reads, offs/deg arrays. agg math/gather
// path byte-identical (fabric-bound part untouched); agg-phase occupancy
// rises to the 32-waves/CU cap. gemm_bin/wprep byte-identical to R10.

typedef short bfvec8 __attribute__((ext_vector_type(8)));  // 8 bf16 (4 VGPRs)
typedef float f32x4  __attribute__((ext_vector_type(4)));

#define BK 128      // nodes per bucket (bucket id = row >> 7)
#define CAPC 3584   // static bucket capacity (mean 2048, sd 45 -> +34 sigma)
#define EPB 8192    // edges per bin sub-block
#define REC 256     // xls record bytes: 128 bf16 x_l, 256B-aligned
#define BSTR 16     // bcur stride in ints: one counter per 64B line

__device__ __forceinline__ unsigned short f2bf(float f) {
  union { float f; unsigned int i; } v; v.f = f;
  unsigned int r = v.i + 0x7fffu + ((v.i >> 16) & 1u);  // RNE
  return (unsigned short)(r >> 16);
}

// ---------------------------------------------------------------------------
// Wt[y][n][k] bf16, n<128 -> W^T. y=0 rows 128..131 = a1w^T*log2e,
// 132..135 = a2w^T*log2e. Blocks (x<8, y=0) also init bcur (folded init_k).
__global__ __launch_bounds__(128) void wprep_k(
    const float* __restrict__ Wl, const float* __restrict__ Wr,
    const float* __restrict__ a1w, const float* __restrict__ a2w,
    unsigned short* __restrict__ Wtg, int* __restrict__ bcur, int NBK)
{
  const int n = blockIdx.x;      // 0..135
  const int y = blockIdx.y;      // 0..1
  const int k = threadIdx.x;     // 0..127
  if (y == 0 && n < 8) {
    int b = n * 128 + k;
    if (b < NBK) bcur[b * BSTR] = b * CAPC;
  }
  const float* W = y ? Wr : Wl;
  const float LOG2E = 1.4426950408889634f;
  float v;
  if (n < 128)      v = W[(size_t)k * 128 + n];
  else if (y)       v = 0.f;                                  // unused
  else if (n < 132) v = a1w[k * 4 + (n - 128)] * LOG2E;
  else              v = a2w[k * 4 + (n - 132)] * LOG2E;
  Wtg[((size_t)y * 136 + n) * 128 + k] = f2bf(v);
}

// ---------------------------------------------------------------------------
// FUSED kernel: role-split blocks (bid%3==0 -> bin, first 196 slots).
//   role GEMM: 64 x-rows, both y passes. x-fragments in regs (afx[4], one
//     load); W staged per-y into XOR-swizzled LDS [128][128] (32KB);
//     a-tile rows (y=0) in regs from L2-hot global.
//     SWAPPED MFMA (D^T): lane (m,quad) owns one x-row, 4 consecutive
//     out-cols per n-tile -> vectorized stores.
//     y=0: xls = x@W_l (bf16), s1 = x@a1w', s2 = x@a2w'; y=1: out=x@W_r+bias.
//   role BIN: ticketed binning of EPB=8192 edges (32/thread in rloc[32]).
//     LDS hist -> ONE global atomic per (block, nonempty bucket) ->
//     LDS-ranked scatter into binned. Entry packed: (r&127)<<17 | c.
__global__ __launch_bounds__(256) void gemm_bin_k(
    const float* __restrict__ x, const unsigned short* __restrict__ Wtg,
    const float* __restrict__ bias,
    char* __restrict__ xls, float* __restrict__ out,
    float* __restrict__ s1, float* __restrict__ s2, int N,
    const int* __restrict__ row, const int* __restrict__ col,
    int* __restrict__ bcur, unsigned int* __restrict__ binned,
    int E, int NBK, int binBlocks, int gemmBlocks)
{
  __shared__ __align__(16) char raw[32768];   // gemm: Ws[128][128]; bin: h/base
  const int bid = blockIdx.x;
  const int t = threadIdx.x;
  const bool isbin = (bid % 3 == 0) && (bid / 3 < binBlocks);

  if (isbin) {
    // ---------------- BIN role ----------------
    int* h    = (int*)raw;            // [NBK] counts / cursors
    int* base = (int*)(raw + 4096);   // [NBK] global bases
    const int sub = bid / 3;
    const int e0 = sub * EPB;
    const int e1 = min(e0 + EPB, E);

    int rloc[32];
    for (int i = t; i < NBK; i += 256) h[i] = 0;
    __syncthreads();
    #pragma unroll
    for (int k = 0; k < 32; ++k) {
      int e = e0 + t + (k << 8);
      rloc[k] = (e < e1) ? row[e] : -1;
      if (rloc[k] >= 0) atomicAdd(&h[rloc[k] >> 7], 1);
    }
    __syncthreads();
    for (int i = t; i < NBK; i += 256) {
      int c = h[i];
      base[i] = c ? atomicAdd(&bcur[i * BSTR], c) : 0;
    }
    __syncthreads();
    for (int i = t; i < NBK; i += 256) h[i] = 0;   // reuse as local cursor
    __syncthreads();
    #pragma unroll
    for (int k = 0; k < 32; ++k) {
      int e = e0 + t + (k << 8);
      if (e < e1) {
        int r = rloc[k];
        unsigned c = (unsigned)col[e];
        int b = r >> 7;
        int rk = atomicAdd(&h[b], 1);
        binned[base[b] + rk] = ((unsigned)(r & 127) << 17) | c;
      }
    }
    return;
  }

  // ---------------- GEMM role ----------------
  unsigned short* Ws = (unsigned short*)raw;   // [128][128], XOR-swizzled 16B groups
  const int sub = bid - min(bid / 3 + 1, binBlocks);
  if (sub >= gemmBlocks) return;
  const int n0 = sub * 64;

  const int w    = t >> 6;
  const int lane = t & 63;
  const int m    = lane & 15;
  const int m7   = m & 7;
  const int quad = lane >> 4;
  const int nrow = n0 + 16 * w + m;   // this lane's single output row
  const int kb   = quad * 8;          // k-offset within each 32-wide chunk

  // x fragments: 8 fp32 -> bf16x8 per k-chunk, loaded ONCE, reused both y.
  bfvec8 afx[4];
  #pragma unroll
  for (int kc4 = 0; kc4 < 4; ++kc4) {
    f32x4 u = (f32x4){0.f, 0.f, 0.f, 0.f};
    f32x4 v = (f32x4){0.f, 0.f, 0.f, 0.f};
    if (nrow < N) {
      const float* xp = &x[(size_t)nrow * 128 + kc4 * 32 + kb];
      u = *(const f32x4*)xp;
      v = *(const f32x4*)(xp + 4);
    }
    bfvec8 a;
    a[0] = (short)f2bf(u[0]); a[1] = (short)f2bf(u[1]);
    a[2] = (short)f2bf(u[2]); a[3] = (short)f2bf(u[3]);
    a[4] = (short)f2bf(v[0]); a[5] = (short)f2bf(v[1]);
    a[6] = (short)f2bf(v[2]); a[7] = (short)f2bf(v[3]);
    afx[kc4] = a;
  }

  // a-tile rows (y=0 extra tile) straight from L2-hot global into regs
  bfvec8 ar[4];
  {
    int arow = 128 + (m < 8 ? m : 7);
    #pragma unroll
    for (int kc4 = 0; kc4 < 4; ++kc4)
      ar[kc4] = *(const bfvec8*)&Wtg[(size_t)arow * 128 + kc4 * 32 + kb];
  }

  #pragma unroll
  for (int y = 0; y < 2; ++y) {
    const unsigned short* Wt = Wtg + (size_t)y * 136 * 128;
    if (y) __syncthreads();          // all waves done reading Ws of y=0
    // cooperative W stage: group g of row nr lands at g ^ (nr&7)
    for (int i = t; i < 2048; i += 256) {
      int nr = i >> 4, g = i & 15;
      int gs = (g ^ (nr & 7)) << 3;
      *(uint4*)&Ws[nr * 128 + gs] = *(const uint4*)&Wt[(size_t)nr * 128 + (g << 3)];
    }
    __syncthreads();

    f32x4 acc[9];
    #pragma unroll
    for (int i = 0; i < 9; ++i) acc[i] = (f32x4){0.f, 0.f, 0.f, 0.f};

    #pragma unroll
    for (int kc4 = 0; kc4 < 4; ++kc4) {
      #pragma unroll
      for (int nt = 0; nt < 8; ++nt) {
        int g = kc4 * 4 + quad;                  // logical 16B group
        bfvec8 bfr = *(const bfvec8*)&Ws[(nt * 16 + m) * 128 + ((g ^ m7) << 3)];
        acc[nt] = __builtin_amdgcn_mfma_f32_16x16x32_bf16(bfr, afx[kc4], acc[nt], 0, 0, 0);
      }
      if (y == 0)
        acc[8] = __builtin_amdgcn_mfma_f32_16x16x32_bf16(ar[kc4], afx[kc4], acc[8], 0, 0, 0);
    }

    if (nrow < N) {
      if (y) {
        #pragma unroll
        for (int nt = 0; nt < 8; ++nt) {
          int c = nt * 16 + quad * 4;
          float4 b4 = *(const float4*)&bias[c];
          float4 v = make_float4(acc[nt][0] + b4.x, acc[nt][1] + b4.y,
                                 acc[nt][2] + b4.z, acc[nt][3] + b4.w);
          *(float4*)&out[(size_t)nrow * 128 + c] = v;
        }
      } else {
        #pragma unroll
        for (int nt = 0; nt < 8; ++nt) {
          int c = nt * 16 + quad * 4;
          unsigned lo = (unsigned)f2bf(acc[nt][0]) | ((unsigned)f2bf(acc[nt][1]) << 16);
          unsigned hi = (unsigned)f2bf(acc[nt][2]) | ((unsigned)f2bf(acc[nt][3]) << 16);
          *(uint2*)(xls + ((size_t)nrow << 8) + 2 * c) = make_uint2(lo, hi);
        }
        if (quad == 0) *(f32x4*)&s1[nrow * 4] = acc[8];      // a-cols 0..3
        else if (quad == 1) *(f32x4*)&s2[nrow * 4] = acc[8]; // a-cols 4..7
      }
    }
  }
}

// ---------------------------------------------------------------------------
// FUSED csr+agg: block b owns bucket b (128 nodes).
// Phase 1 (csr): binned window -> ecache (LDS), hist -> scan -> LDS-cursor
// scatter of premultiplied cols (c<<8) into scol (LDS). NO global colsort.
// Phase 2 (agg): 16 waves x 8 nodes each. Per node: 8-chunk dedup-softmax
// agg loop (identical math to R10's agg_k) with edge bases read from scol.
__global__ __launch_bounds__(1024) void csragg_k(
    const unsigned int* __restrict__ binned, const int* __restrict__ bcur,
    const float* __restrict__ s1, const float* __restrict__ s2,
    const char* __restrict__ xls, float* __restrict__ out, int N)
{
  __shared__ unsigned ecache[CAPC];   // 14.3KB packed entries
  __shared__ unsigned scol[CAPC];     // 14.3KB sorted premultiplied cols
  __shared__ int h[BK];               // cursor (end offsets after scatter)
  __shared__ int sh[BK];
  __shared__ int dg[BK];
  const int t = threadIdx.x;
  const int b = blockIdx.x;
  const int lo = b * BK;
  const int e0g = b * CAPC;
  const int e1g = bcur[b * BSTR];   // e0g + cnt

  // ---- phase 1: bucket sort into LDS ----
  if (t < BK) h[t] = 0;
  __syncthreads();
  for (int i = e0g + t; i < e1g; i += 1024) {
    unsigned p = binned[i];
    ecache[i - e0g] = p;
    atomicAdd(&h[p >> 17], 1);
  }
  __syncthreads();
  int v = 0;
  if (t < BK) { v = h[t]; sh[t] = v; dg[t] = v; }
  __syncthreads();
  for (int off = 1; off < BK; off <<= 1) {
    int tv = (t < BK && t >= off) ? sh[t - off] : 0;
    __syncthreads();
    if (t < BK) sh[t] += tv;
    __syncthreads();
  }
  if (t < BK) h[t] = sh[t] - v;     // exclusive start, reused as cursor
  __syncthreads();
  const int cnt = e1g - e0g;
  for (int i = t; i < cnt; i += 1024) {
    unsigned p = ecache[i];
    int pos = atomicAdd(&h[p >> 17], 1);
    scol[pos] = (p & 0x1FFFFu) << 8;   // premultiplied byte base (REC=256)
  }
  __syncthreads();
  // h[nl] is now END offset; start = h[nl] - dg[nl]

  // ---- phase 2: aggregate 128 nodes, 16 waves x 8 nodes ----
  const int wvi  = t >> 6;           // wave 0..15
  const int lane = t & 63;
  const int hd   = lane >> 4;        // accumulation head
  const int hp   = lane & 3;         // softmax head
  const int jj   = (lane >> 2) & 7;  // softmax edge slot
  const unsigned lane4 = (unsigned)(lane << 2);
  const unsigned hp4   = (unsigned)(hp << 2);
  const char* s2b = (const char*)s2;

  for (int q = 0; q < 8; ++q) {
    const int nl = wvi * 8 + q;
    const int node = lo + nl;
    if (node >= N) break;
    const int eS = h[nl] - dg[nl];
    const int eE = h[nl];
    const float s1c = s1[node * 4 + hp];           // pre-scaled by log2e

    float acc0 = 0.f, acc1 = 0.f, wsum = 0.f;
    int i0 = eS;
    for (; i0 + 8 <= eE; i0 += 8) {
      unsigned csl = scol[i0 + jj];                        // LDS
      float z2 = *(const float*)(s2b + ((csl >> 4) + hp4));
      float z = s1c + z2;
      z = fmaxf(z, 0.2f * z);                              // leaky
      float wv = exp2f(z);                                 // ONE v_exp_f32

      unsigned cs[8];
      #pragma unroll
      for (int j = 0; j < 8; ++j) cs[j] = scol[i0 + j];    // LDS broadcast
      unsigned pv[8];
      #pragma unroll
      for (int j = 0; j < 8; ++j)
        pv[j] = *(const unsigned*)(xls + (cs[j] + lane4)); // 8 indep gathers

      #pragma unroll
      for (int j = 0; j < 8; ++j) {
        float wj = __shfl(wv, (j << 2) | hd);              // ds_bpermute
        wsum += wj;
        union { unsigned u; float f; } lof, hif;
        lof.u = pv[j] << 16;
        hif.u = pv[j] & 0xffff0000u;
        acc0 += wj * lof.f;
        acc1 += wj * hif.f;
      }
    }
    if (i0 < eE) {                   // masked parallel tail chunk (rem 1..7)
      const int rem = eE - i0;
      unsigned csl = scol[i0 + (jj < rem ? jj : rem - 1)];
      float z2 = *(const float*)(s2b + ((csl >> 4) + hp4));
      float z = s1c + z2;
      z = fmaxf(z, 0.2f * z);
      float wv = (jj < rem) ? exp2f(z) : 0.f;

      unsigned cs[8];
      #pragma unroll
      for (int j = 0; j < 8; ++j) cs[j] = scol[i0 + (j < rem ? j : rem - 1)];
      unsigned pv[8];
      #pragma unroll
      for (int j = 0; j < 8; ++j)
        pv[j] = *(const unsigned*)(xls + (cs[j] + lane4));

      #pragma unroll
      for (int j = 0; j < 8; ++j) {
        float wj = __shfl(wv, (j << 2) | hd);              // 0 for j>=rem
        wsum += wj;
        union { unsigned u; float f; } lof, hif;
        lof.u = pv[j] << 16;
        hif.u = pv[j] & 0xffff0000u;
        acc0 += wj * lof.f;
        acc1 += wj * hif.f;
      }
    }

    float inv = (wsum > 0.f) ? (1.0f / wsum) : 0.f;
    const size_t o = (size_t)node * 128 + 2 * lane;
    float2 xr = *(const float2*)&out[o];
    float2 res; res.x = acc0 * inv + xr.x; res.y = acc1 * inv + xr.y;
    *(float2*)&out[o] = res;
  }
}

// ---------------------------------------------------------------------------
extern "C" void kernel_launch(void* const* d_in, const int* in_sizes, int n_in,
                              void* d_out, int out_size, void* d_ws, size_t ws_size,
                              hipStream_t stream) {
  const float* x    = (const float*)d_in[0];
  const int*   row  = (const int*)d_in[1];
  const int*   col  = (const int*)d_in[2];
  const float* Wl   = (const float*)d_in[3];
  const float* Wr   = (const float*)d_in[4];
  const float* a1w  = (const float*)d_in[5];
  const float* a2w  = (const float*)d_in[6];
  const float* bias = (const float*)d_in[7];
  float* out = (float*)d_out;
  const int N = in_sizes[0] / 128;
  const int E = in_sizes[1];
  (void)n_in; (void)out_size; (void)ws_size;

  const int NBK = (N + BK - 1) / BK;   // 782 for N=100K (<=1024 required)

  char* ws = (char*)d_ws;
  size_t off = 0;
  auto carve = [&](size_t bytes) { void* p = ws + off; off += (bytes + 255) & ~(size_t)255; return p; };
  char* xls            = (char*)carve((size_t)N * REC);                 // 25.6 MB, 256B-aligned
  float* s1            = (float*)carve((size_t)N * 4 * 4);
  float* s2            = (float*)carve((size_t)N * 4 * 4);              // 1.6 MB, L2-resident
  unsigned int* binned = (unsigned int*)carve((size_t)NBK * CAPC * 4);  // 11.2 MB
  int* bcur            = (int*)carve((size_t)NBK * BSTR * 4);           // padded: 1/line
  unsigned short* Wtg  = (unsigned short*)carve((size_t)2 * 136 * 128 * 2);

  const int gemmBlocks = (N + 63) / 64;          // 1563
  const int binBlocks  = (E + EPB - 1) / EPB;    // 196
  const int T = gemmBlocks + binBlocks;          // 1759

  wprep_k   <<<dim3(136, 2), 128, 0, stream>>>(Wl, Wr, a1w, a2w, Wtg, bcur, NBK);
  gemm_bin_k<<<T, 256, 0, stream>>>(x, Wtg, bias, xls, out, s1, s2, N,
                                    row, col, bcur, binned, E, NBK,
                                    binBlocks, gemmBlocks);
  csragg_k  <<<NBK, 1024, 0, stream>>>(binned, bcur, s1, s2, xls, out, N);
}